// Round 17
// baseline (913.556 us; speedup 1.0000x reference)
//
#include <hip/hip_runtime.h>

#define BATCH   512
#define TSTEPS  50
#define NIN     784
#define NHID    800
#define NOUT    10
#define KC      384   // OpenBLAS SGEMM_DEFAULT_Q — panel folds at k=384, 768

typedef float v4f __attribute__((ext_vector_type(4)));

// ---------------------------------------------------------------------------
// Panel GEMM (NT): ONE KC-panel ascending-k FMA chain per output element.
// 128x160 tile (5 n-tiles cover N=800 EXACTLY -> zero dead-column FMAs;
// the old 128-wide tiling wasted 10.7% on the 7th tile), 320 threads
// (20 tx x 16 ty), 8x8 micro, BK=8, k-major LDS, 12-float swizzled B,
// named-float4 accumulators (round 14), LDS double-buffer (round 16).
// NO inline asm (round 15: "+v" forces AGPR->VGPR copies, 2x VALU).
// Requires M%128==0, N%160==0, (ke-ks)%8==0.
// ---------------------------------------------------------------------------
#define ROW_FMA(pl, ph, as)                       \
    pl.x = __fmaf_rn(as, blo.x, pl.x);            \
    pl.y = __fmaf_rn(as, blo.y, pl.y);            \
    pl.z = __fmaf_rn(as, blo.z, pl.z);            \
    pl.w = __fmaf_rn(as, blo.w, pl.w);            \
    ph.x = __fmaf_rn(as, bhi.x, ph.x);            \
    ph.y = __fmaf_rn(as, bhi.y, ph.y);            \
    ph.z = __fmaf_rn(as, bhi.z, ph.z);            \
    ph.w = __fmaf_rn(as, bhi.w, ph.w);

#define STORE_ROW(i, pl, ph)                                        \
    {   float* crow = Cp + (size_t)(m0 + 8*ty + (i)) * N + cb;      \
        *(float4*)crow = pl;                                        \
        *(float4*)(crow + 4) = ph; }

__global__ __launch_bounds__(320)
void gemm_panel_f32(const float* __restrict__ A, const float* __restrict__ B,
                    float* __restrict__ Cp, int M, int N, int K,
                    int ks, int ke)
{
    __shared__ float As[2][8][132];   // [buf][k][m]
    __shared__ float Bs[2][8][236];   // [buf][k][phys(n)], phys=12*(n>>3)+(n&7)

    const int tid = threadIdx.x;
    const int tx = tid % 20;        // n micro: 8 cols at 8*tx   (0..19)
    const int ty = tid / 20;        // m micro: 8 rows at 8*ty   (0..15)
    const int m0 = blockIdx.x * 128;
    const int n0 = blockIdx.y * 160;

    // staging: A uses threads 0..255 (128 rows x 2 float4-loaders);
    //          B uses all 320 (160 rows x 2 loaders)
    const int sra  = tid >> 1;          // A row 0..159 (use <128)
    const int skq  = (tid & 1) * 4;     // 0 or 4
    const int bphys = 12 * (sra >> 3) + (sra & 7);
    const bool aact = (sra < 128);

    const float* Aptr = A + (size_t)(m0 + (aact ? sra : 0)) * K + skq;
    const float* Bptr = B + (size_t)(n0 + sra) * K + skq;

    float4 p0l = {0,0,0,0}, p0h = {0,0,0,0}, p1l = {0,0,0,0}, p1h = {0,0,0,0};
    float4 p2l = {0,0,0,0}, p2h = {0,0,0,0}, p3l = {0,0,0,0}, p3h = {0,0,0,0};
    float4 p4l = {0,0,0,0}, p4h = {0,0,0,0}, p5l = {0,0,0,0}, p5h = {0,0,0,0};
    float4 p6l = {0,0,0,0}, p6h = {0,0,0,0}, p7l = {0,0,0,0}, p7h = {0,0,0,0};

    // prologue: chunk ks -> buf 0
    {
        float4 av = *(const float4*)(Aptr + ks);
        float4 bv = *(const float4*)(Bptr + ks);
        if (aact) {
            As[0][skq+0][sra] = av.x; As[0][skq+1][sra] = av.y;
            As[0][skq+2][sra] = av.z; As[0][skq+3][sra] = av.w;
        }
        Bs[0][skq+0][bphys] = bv.x; Bs[0][skq+1][bphys] = bv.y;
        Bs[0][skq+2][bphys] = bv.z; Bs[0][skq+3][bphys] = bv.w;
    }
    __syncthreads();

    int cur = 0;
    for (int k0 = ks; k0 < ke; k0 += 8) {
        const bool more = (k0 + 8 < ke);

        // prefetch next chunk into registers (issue before compute)
        float4 av, bv;
        if (more) {
            av = *(const float4*)(Aptr + k0 + 8);
            bv = *(const float4*)(Bptr + k0 + 8);
        }

        #pragma unroll
        for (int kk = 0; kk < 8; ++kk) {
            const float4 alo = *(const float4*)&As[cur][kk][8*ty];
            const float4 ahi = *(const float4*)&As[cur][kk][8*ty + 4];
            const float4 blo = *(const float4*)&Bs[cur][kk][12*tx];
            const float4 bhi = *(const float4*)&Bs[cur][kk][12*tx + 4];
            ROW_FMA(p0l, p0h, alo.x)
            ROW_FMA(p1l, p1h, alo.y)
            ROW_FMA(p2l, p2h, alo.z)
            ROW_FMA(p3l, p3h, alo.w)
            ROW_FMA(p4l, p4h, ahi.x)
            ROW_FMA(p5l, p5h, ahi.y)
            ROW_FMA(p6l, p6h, ahi.z)
            ROW_FMA(p7l, p7h, ahi.w)
        }

        if (more) {
            const int nx = cur ^ 1;
            if (aact) {
                As[nx][skq+0][sra] = av.x; As[nx][skq+1][sra] = av.y;
                As[nx][skq+2][sra] = av.z; As[nx][skq+3][sra] = av.w;
            }
            Bs[nx][skq+0][bphys] = bv.x; Bs[nx][skq+1][bphys] = bv.y;
            Bs[nx][skq+2][bphys] = bv.z; Bs[nx][skq+3][bphys] = bv.w;
            __syncthreads();
        }
        cur ^= 1;
    }

    const int cb = n0 + 8 * tx;
    STORE_ROW(0, p0l, p0h)
    STORE_ROW(1, p1l, p1h)
    STORE_ROW(2, p2l, p2h)
    STORE_ROW(3, p3l, p3h)
    STORE_ROW(4, p4l, p4h)
    STORE_ROW(5, p5l, p5h)
    STORE_ROW(6, p6l, p6h)
    STORE_ROW(7, p7l, p7h)
}

// ---------------------------------------------------------------------------
// 800x800 transpose: W2T[k][n] = W2[n][k]
// ---------------------------------------------------------------------------
__global__ __launch_bounds__(256)
void transpose800(const float* __restrict__ W2, float* __restrict__ W2T)
{
    __shared__ float t[32][33];
    const int tx  = threadIdx.x & 31;
    const int ty8 = threadIdx.x >> 5;
    const int bx = blockIdx.x * 32, by = blockIdx.y * 32;

    #pragma unroll
    for (int r = 0; r < 4; ++r) {
        int a = ty8 + r * 8;
        t[a][tx] = W2[(size_t)(by + a) * 800 + bx + tx];
    }
    __syncthreads();
    #pragma unroll
    for (int r = 0; r < 4; ++r) {
        int a = ty8 + r * 8;
        W2T[(size_t)(bx + a) * 800 + by + tx] = t[tx][a];
    }
}

// ---------------------------------------------------------------------------
// Layer-1 LIF scan with fused P3 (k=768..784 chain) — proven round 14.
// z = ((P1 + P2) + P3); m = ((0.95f*m)+z)+b; s=(m>thr); mult reset; bitmask.
// ---------------------------------------------------------------------------
__global__ __launch_bounds__(256)
void lif_scan_hid1(const float* __restrict__ Z0,
                   const float* __restrict__ Z1,
                   const float* __restrict__ xc,   // x + t0*BATCH*NIN
                   const float* __restrict__ W1,
                   const float* __restrict__ bias,
                   const float* __restrict__ budget,
                   float* __restrict__ mcarry,
                   float* __restrict__ Sout,
                   unsigned long long* __restrict__ bm,
                   int CT, int t0)
{
    __shared__ float W1s[NHID][17];

    const int b = blockIdx.x;
    const int tid = threadIdx.x;
    const int lane = tid & 63;
    const int wave = tid >> 6;

    for (int q = tid; q < NHID * 16; q += 256)
        W1s[q >> 4][q & 15] = W1[(size_t)(q >> 4) * NIN + 768 + (q & 15)];
    __syncthreads();

    float m[4], thr[4], bj[4];
    bool val[4];
    int jjv[4];
    #pragma unroll
    for (int c = 0; c < 4; ++c) {
        const int j = c * 256 + tid;
        val[c] = (j < NHID);
        const int jj = val[c] ? j : 0;
        jjv[c] = jj;
        float bu = budget[jj];
        bu = fminf(fmaxf(bu, 0.01f), 1.0f);
        thr[c] = __fdiv_rn(1.0f, bu);
        bj[c]  = bias[jj];
        m[c]   = mcarry[b * NHID + jj];
    }

    for (int ct = 0; ct < CT; ++ct) {
        const size_t zbase = (size_t)ct * (BATCH * NHID) + (size_t)b * NHID;
        const size_t sbase = (size_t)(t0 + ct) * (BATCH * NHID) + (size_t)b * NHID;
        const float* xr = xc + ((size_t)ct * BATCH + b) * NIN + 768;
        const float4 x0 = *(const float4*)(xr);
        const float4 x1 = *(const float4*)(xr + 4);
        const float4 x2 = *(const float4*)(xr + 8);
        const float4 x3 = *(const float4*)(xr + 12);

        #pragma unroll
        for (int c = 0; c < 4; ++c) {
            const int j = c * 256 + tid;
            bool sp = false;
            if (val[c]) {
                const int jj = jjv[c];
                float z = __fadd_rn(__builtin_nontemporal_load(Z0 + zbase + j),
                                    __builtin_nontemporal_load(Z1 + zbase + j));
                float p3 = 0.0f;
                p3 = __fmaf_rn(x0.x, W1s[jj][0],  p3);
                p3 = __fmaf_rn(x0.y, W1s[jj][1],  p3);
                p3 = __fmaf_rn(x0.z, W1s[jj][2],  p3);
                p3 = __fmaf_rn(x0.w, W1s[jj][3],  p3);
                p3 = __fmaf_rn(x1.x, W1s[jj][4],  p3);
                p3 = __fmaf_rn(x1.y, W1s[jj][5],  p3);
                p3 = __fmaf_rn(x1.z, W1s[jj][6],  p3);
                p3 = __fmaf_rn(x1.w, W1s[jj][7],  p3);
                p3 = __fmaf_rn(x2.x, W1s[jj][8],  p3);
                p3 = __fmaf_rn(x2.y, W1s[jj][9],  p3);
                p3 = __fmaf_rn(x2.z, W1s[jj][10], p3);
                p3 = __fmaf_rn(x2.w, W1s[jj][11], p3);
                p3 = __fmaf_rn(x3.x, W1s[jj][12], p3);
                p3 = __fmaf_rn(x3.y, W1s[jj][13], p3);
                p3 = __fmaf_rn(x3.z, W1s[jj][14], p3);
                p3 = __fmaf_rn(x3.w, W1s[jj][15], p3);
                z = __fadd_rn(z, p3);

                float mm = __fadd_rn(__fadd_rn(__fmul_rn(0.95f, m[c]), z), bj[c]);
                sp = (mm > thr[c]);
                m[c] = sp ? 0.0f : mm;
                __builtin_nontemporal_store(sp ? 1.0f : 0.0f, Sout + sbase + j);
            }
            unsigned long long bits = __ballot(sp);
            if (lane == 0) {
                const int W = c * 4 + wave;
                if (W < 13)
                    bm[((size_t)ct * BATCH + b) * 13 + W] = bits;
            }
        }
    }
    #pragma unroll
    for (int c = 0; c < 4; ++c)
        if (val[c]) mcarry[b * NHID + c * 256 + tid] = m[c];
}

// ---------------------------------------------------------------------------
// Layer-2 LIF scan (single-panel z), no bitmask.
// ---------------------------------------------------------------------------
__global__ __launch_bounds__(256)
void lif_scan_hid2(const float* __restrict__ Z0,
                   const float* __restrict__ bias,
                   const float* __restrict__ budget,
                   float* __restrict__ mcarry,
                   float* __restrict__ Sout,
                   int CT, int t0)
{
    const int b = blockIdx.x;
    const int tid = threadIdx.x;

    float m[4], thr[4], bj[4];
    bool val[4];
    #pragma unroll
    for (int c = 0; c < 4; ++c) {
        const int j = c * 256 + tid;
        val[c] = (j < NHID);
        const int jj = val[c] ? j : 0;
        float bu = budget[jj];
        bu = fminf(fmaxf(bu, 0.01f), 1.0f);
        thr[c] = __fdiv_rn(1.0f, bu);
        bj[c]  = bias[jj];
        m[c]   = mcarry[b * NHID + jj];
    }

    for (int ct = 0; ct < CT; ++ct) {
        const size_t zbase = (size_t)ct * (BATCH * NHID) + (size_t)b * NHID;
        const size_t sbase = (size_t)(t0 + ct) * (BATCH * NHID) + (size_t)b * NHID;
        #pragma unroll
        for (int c = 0; c < 4; ++c) {
            const int j = c * 256 + tid;
            if (val[c]) {
                float z = __builtin_nontemporal_load(Z0 + zbase + j);
                float mm = __fadd_rn(__fadd_rn(__fmul_rn(0.95f, m[c]), z), bj[c]);
                bool sp = (mm > thr[c]);
                m[c] = sp ? 0.0f : mm;
                __builtin_nontemporal_store(sp ? 1.0f : 0.0f, Sout + sbase + j);
            }
        }
    }
    #pragma unroll
    for (int c = 0; c < 4; ++c)
        if (val[c]) mcarry[b * NHID + c * 256 + tid] = m[c];
}

// ---------------------------------------------------------------------------
// Sparse spike GEMM — round-6 proven version (~276 us, AT its L2 roofline:
// 9.5 GB / 34.5 TB/s). Block per row; bitmask -> ordered k-list in LDS,
// wave-uniform walk; panel folds tracked by k index. Do not touch.
// ---------------------------------------------------------------------------
__global__ __launch_bounds__(256)
void spmm_spikes(const unsigned long long* __restrict__ bm, // [rows][13]
                 const float* __restrict__ W2T,             // [800][800]
                 float* __restrict__ Z,                     // [rows][800]
                 int rows)
{
    __shared__ unsigned long long wbuf[13];
    __shared__ unsigned short list[NHID];
    __shared__ int offs[14];

    const int tid = threadIdx.x;
    const int lane = tid & 63;
    const int wave = tid >> 6;
    const int row = blockIdx.x;

    if (tid < 13) wbuf[tid] = bm[(size_t)row * 13 + tid];
    __syncthreads();
    if (tid == 0) {
        int o = 0;
        for (int w = 0; w < 13; ++w) { offs[w] = o; o += __popcll(wbuf[w]); }
        offs[13] = o;
    }
    __syncthreads();
    for (int W = wave; W < 13; W += 4) {
        const unsigned long long bits = wbuf[W];
        const int pre = __popcll(bits & ((1ull << lane) - 1ull));
        if ((bits >> lane) & 1ull)
            list[offs[W] + pre] = (unsigned short)(W * 64 + lane);
    }
    __syncthreads();
    const int nnz = offs[13];

    if (tid < 200) {
        const int n = 4 * tid;
        float p0 = 0.f, p1 = 0.f, p2 = 0.f, p3 = 0.f;
        float a0 = 0.f, a1 = 0.f, a2 = 0.f, a3 = 0.f;
        int p = 0, nextb = KC;          // 384 then 768 then "never"
        for (int i = 0; i < nnz; ++i) {
            const int k = list[i];
            while (k >= nextb) {
                if (p == 0) { a0 = p0; a1 = p1; a2 = p2; a3 = p3; }
                else {
                    a0 = __fadd_rn(a0, p0); a1 = __fadd_rn(a1, p1);
                    a2 = __fadd_rn(a2, p2); a3 = __fadd_rn(a3, p3);
                }
                p0 = p1 = p2 = p3 = 0.f; ++p;
                nextb = (nextb == KC) ? 2 * KC : 100000;
            }
            const float4 w = *(const float4*)(W2T + (size_t)k * NHID + n);
            p0 = __fadd_rn(p0, w.x); p1 = __fadd_rn(p1, w.y);
            p2 = __fadd_rn(p2, w.z); p3 = __fadd_rn(p3, w.w);
        }
        while (p < 3) {                 // close remaining panels (K=800 -> 3)
            if (p == 0) { a0 = p0; a1 = p1; a2 = p2; a3 = p3; }
            else {
                a0 = __fadd_rn(a0, p0); a1 = __fadd_rn(a1, p1);
                a2 = __fadd_rn(a2, p2); a3 = __fadd_rn(a3, p3);
            }
            p0 = p1 = p2 = p3 = 0.f; ++p;
        }
        *(float4*)(Z + (size_t)row * NHID + n) = make_float4(a0, a1, a2, a3);
    }
}

// ---------------------------------------------------------------------------
// Layer-3 GEMM, float4 loads, chain preserved (folds at float4 idx 96/192).
// ---------------------------------------------------------------------------
__global__ __launch_bounds__(256)
void gemm3_f32(const float* __restrict__ S2, const float* __restrict__ W3,
               float* __restrict__ Z3, int rows)
{
    int gid = blockIdx.x * 256 + threadIdx.x;
    if (gid >= rows * NOUT) return;
    const int m = gid / NOUT;
    const int nn = gid % NOUT;
    const float* a = S2 + (size_t)m * NHID;
    const float* wr = W3 + (size_t)nn * NHID;

    float part = 0.0f, acc = 0.0f;
    int p = 0;
    for (int i = 0; i < NHID / 4; ++i) {
        if (i == 96 || i == 192) {
            acc = (p == 0) ? part : __fadd_rn(acc, part);
            part = 0.0f; ++p;
        }
        const v4f a4 = __builtin_nontemporal_load((const v4f*)(a + 4 * i));
        const float4 w4 = *(const float4*)(wr + 4 * i);
        part = __fmaf_rn(a4.x, w4.x, part);
        part = __fmaf_rn(a4.y, w4.y, part);
        part = __fmaf_rn(a4.z, w4.z, part);
        part = __fmaf_rn(a4.w, w4.w, part);
    }
    acc = (p == 0) ? part : __fadd_rn(acc, part);
    Z3[gid] = acc;
}

// ---------------------------------------------------------------------------
__global__ __launch_bounds__(256)
void lif_scan_small(const float* __restrict__ Z, const float* __restrict__ bias,
                    float* __restrict__ mcarry, float* __restrict__ Sout,
                    int CT, int t0)
{
    const int idx = blockIdx.x * blockDim.x + threadIdx.x;
    const int total = BATCH * NOUT;
    if (idx >= total) return;
    const int j = idx % NOUT;
    const float thr = 1.0f;
    const float bj = bias[j];

    float m = mcarry[idx];
    for (int ct = 0; ct < CT; ++ct) {
        float z = Z[(size_t)ct * total + idx];
        m = __fadd_rn(__fadd_rn(__fmul_rn(0.95f, m), z), bj);
        float s;
        if (m > thr) { s = 1.0f; m = 0.0f; }
        else         { s = 0.0f; }
        Sout[(size_t)(t0 + ct) * total + idx] = s;
    }
    mcarry[idx] = m;
}

// ---------------------------------------------------------------------------
__global__ __launch_bounds__(256)
void sum_t(const float* __restrict__ S3, float* __restrict__ out0)
{
    const int idx = blockIdx.x * blockDim.x + threadIdx.x;
    if (idx >= BATCH * NOUT) return;
    float s = 0.0f;
    for (int t = 0; t < TSTEPS; ++t)
        s += S3[(size_t)t * BATCH * NOUT + idx];
    out0[idx] = s;
}

// ---------------------------------------------------------------------------
extern "C" void kernel_launch(void* const* d_in, const int* in_sizes, int n_in,
                              void* d_out, int out_size, void* d_ws, size_t ws_size,
                              hipStream_t stream)
{
    const float* x       = (const float*)d_in[0];
    const float* W1      = (const float*)d_in[1];
    const float* b1      = (const float*)d_in[2];
    const float* W2      = (const float*)d_in[3];
    const float* b2      = (const float*)d_in[4];
    const float* W3      = (const float*)d_in[5];
    const float* b3      = (const float*)d_in[6];
    const float* budget1 = (const float*)d_in[7];
    const float* budget2 = (const float*)d_in[8];

    float* out  = (float*)d_out;
    float* out0 = out;
    float* out1 = out0 + BATCH * NOUT;
    float* out2 = out1 + (size_t)TSTEPS * BATCH * NHID;
    float* out3 = out2 + (size_t)TSTEPS * BATCH * NHID;

    const size_t nBH = (size_t)BATCH * NHID;     // 409600
    const size_t nBO = (size_t)BATCH * NOUT;     // 5120
    float* m1c = (float*)d_ws;
    float* m2c = m1c + nBH;
    float* m3c = m2c + nBH;
    float* w2t = m3c + nBO;
    unsigned long long* bmask = (unsigned long long*)(w2t + (size_t)NHID * NHID);
    float* Z = (float*)(bmask + (size_t)TSTEPS * BATCH * 13);

    const size_t fixedF = 2 * nBH + nBO + (size_t)NHID * NHID
                        + (size_t)TSTEPS * BATCH * 13 * 2;
    size_t availF = (ws_size / 4 > fixedF) ? (ws_size / 4 - fixedF) : 0;
    // per timestep: 2 Z-panels (layer 1) + Z3
    const size_t perT = (size_t)BATCH * (2 * NHID + NOUT);
    int CT = (int)(availF / perT);
    if (CT > TSTEPS) CT = TSTEPS;
    if (CT < 1) CT = 1;

    hipMemsetAsync(d_ws, 0, (2 * nBH + nBO) * sizeof(float), stream);

    {
        dim3 tg(25, 25);
        transpose800<<<tg, 256, 0, stream>>>(W2, w2t);
    }

    for (int t0 = 0; t0 < TSTEPS; t0 += CT) {
        int ct = TSTEPS - t0 < CT ? TSTEPS - t0 : CT;
        int Mrows = ct * BATCH;
        const size_t pstride = (size_t)ct * BATCH * NHID;
        float* Zp0 = Z;
        float* Zp1 = Z + pstride;
        float* Z3  = Z + 2 * pstride;
        const float* xc = x + (size_t)t0 * BATCH * NIN;

        // layer 1: two K-panels of x_chunk @ W1^T (P3 fused into lif)
        {
            dim3 grid(Mrows / 128, NHID / 160);
            gemm_panel_f32<<<grid, 320, 0, stream>>>(xc, W1, Zp0, Mrows, NHID, NIN, 0,   384);
            gemm_panel_f32<<<grid, 320, 0, stream>>>(xc, W1, Zp1, Mrows, NHID, NIN, 384, 768);
        }
        lif_scan_hid1<<<BATCH, 256, 0, stream>>>(
            Zp0, Zp1, xc, W1, b1, budget1, m1c, out1, bmask, ct, t0);

        // layer 2: sparse Z = s1_chunk @ W2^T via bitmask (1 row/block)
        spmm_spikes<<<Mrows, 256, 0, stream>>>(bmask, w2t, Zp0, Mrows);
        lif_scan_hid2<<<BATCH, 256, 0, stream>>>(
            Zp0, b2, budget2, m2c, out2, ct, t0);

        // layer 3
        gemm3_f32<<<(Mrows * NOUT + 255) / 256, 256, 0, stream>>>(
            out2 + (size_t)t0 * BATCH * NHID, W3, Z3, Mrows);
        lif_scan_small<<<(BATCH * NOUT + 255) / 256, 256, 0, stream>>>(
            Z3, b3, m3c, out3, ct, t0);
    }

    sum_t<<<(BATCH * NOUT + 255) / 256, 256, 0, stream>>>(out3, out0);
}